// Round 10
// baseline (124.506 us; speedup 1.0000x reference)
//
#include <hip/hip_runtime.h>
#include <hip/hip_bf16.h>

#define BB   8
#define SCTX 4096
#define SQ   512
#define EE   300
#define HH   128
#define CST  328    // staged fp32->bf16 E-row stride (shorts)
#define LOG2E 1.4426950408889634f

// HIP predefines short4/float4/uint4 (hip_vector_types.h) — never shadow them.
typedef short bhalf4 __attribute__((ext_vector_type(4)));
typedef short short8 __attribute__((ext_vector_type(8)));
typedef float f32x4  __attribute__((ext_vector_type(4)));
typedef unsigned u32x4 __attribute__((ext_vector_type(4)));

#define MFMA16(a, b, c) __builtin_amdgcn_mfma_f32_16x16x32_bf16((a), (b), (c), 0, 0, 0)
#define SBAR()   __builtin_amdgcn_s_barrier()
#define SCHED0() __builtin_amdgcn_sched_barrier(0)

__device__ __forceinline__ short f2bf(float f) {
  unsigned u = __builtin_bit_cast(unsigned, f);
  u += 0x7fffu + ((u >> 16) & 1u);
  return (short)(u >> 16);
}
__device__ __forceinline__ float bf2f(short s) {
  return __builtin_bit_cast(float, ((unsigned)(unsigned short)s) << 16);
}
__device__ __forceinline__ unsigned pack2(float a, float b) {
  return (unsigned)(unsigned short)f2bf(a) | ((unsigned)(unsigned short)f2bf(b) << 16);
}
// global -> LDS direct DMA, 16 B/lane. LDS dest = wave-uniform base + lane*16 (m104);
// global source is per-lane (swizzle goes on the SOURCE, rule #21).
__device__ __forceinline__ void gload16(const void* g, void* lds) {
  __builtin_amdgcn_global_load_lds(
      (const __attribute__((address_space(1))) void*)g,
      (__attribute__((address_space(3))) void*)lds, 16, 0, 0);
}

// ---------------- kernel 1: qst logits -> ql [b][q][h] + qlT [b][h][q]; also wsw ------
// R20 REDESIGN (k_wpad folded in, dual-layout MFMA, all-b64 stores):
//  * grid (SQ/16, BB) = 256 blocks (was 128; half the CUs sat idle), 16 q-rows each.
//  * W fragments direct-loaded from global (L2-hot, 2x float4, 16-B aligned; kk=9 tail
//    masked per element). k_wpad launch DELETED; the 32 blocks with b==0 write the
//    fragment-swizzled wsw for k_attn (stream order -> visible at k_attn launch).
//  * BOTH operand orders computed (MFMA pipe ~9% busy, extra MFMAs free):
//      acc1 = MFMA16(a, w8): lane(t,quad) r = QL[q=q0+quad*4+r][h=habs+t] -> qlT b64
//      acc2 = MFMA16(w8, a): lane(t,quad) r = QL[q=q0+t][h=habs+quad*4+r] -> ql  b64
//    (D-layout rule verified R15/R18: D[lane(t,quad),r] = Xrow(quad*4+r) . Yrow(t).)
//    Replaces 16 scalar 2-B scatter stores per thread with 4 aligned b64 stores.
__global__ __launch_bounds__(256) void k_qlog(const float* __restrict__ qst,
                                              const float* __restrict__ W,
                                              const float* __restrict__ bias,
                                              short* __restrict__ ql,
                                              short* __restrict__ qlT,
                                              short* __restrict__ wsw) {
  const int b = blockIdx.y;
  const int q0 = blockIdx.x * 16;
  const int tid = threadIdx.x;
  const int w = tid >> 6, l = tid & 63, t = l & 15, quad = l >> 4;

  __shared__ __align__(16) short cst[16 * CST];

  // stage 16 q-rows fp32 -> bf16 (1200 float4)
  const float4* cbase = (const float4*)(qst + (size_t)(b * SQ + q0) * EE);
#pragma unroll
  for (int j = 0; j < 5; ++j) {
    int i4 = tid + j * 256;
    if (i4 < 1200) {
      float4 v = cbase[i4];
      int row = i4 / 75, c4 = i4 - row * 75;
      bhalf4 s4; s4[0] = f2bf(v.x); s4[1] = f2bf(v.y); s4[2] = f2bf(v.z); s4[3] = f2bf(v.w);
      *(bhalf4*)(cst + row * CST + c4 * 4) = s4;
    }
  }
  for (int i = tid; i < 160; i += 256) {        // zero k=300..319 for all 16 rows
    int row = i / 10, c = (i - row * 10) * 2;
    *(int*)&cst[row * CST + 300 + c] = 0;
  }
  // k_wpad folded in: b==0 blocks convert W rows qx*4..+3 into swizzled wsw
  if (b == 0) {
    const int h = blockIdx.x * 4;
#pragma unroll
    for (int j = 0; j < 5; ++j) {
      int i = tid + j * 256;
      int hi = i / 320, k = i - hi * 320;
      float v = (k < EE) ? W[(h + hi) * EE + k] : 0.0f;
      int m = (h + hi) >> 4, tt = (h + hi) & 15, kk = k >> 5, qq = (k >> 3) & 3, jj = k & 7;
      wsw[((kk * 8 + m) * 64 + qq * 16 + tt) * 8 + jj] = f2bf(v);
    }
  }
  __syncthreads();

  // per-wave: h-blocks n ∈ {2w, 2w+1}; dual-layout accumulate
  f32x4 acc1[2] = {}, acc2[2] = {};
  const short* arow = cst + t * CST;
#pragma unroll
  for (int kk = 0; kk < 10; ++kk) {
    short8 a = *(const short8*)(arow + kk * 32 + quad * 8);
#pragma unroll
    for (int n = 0; n < 2; ++n) {
      const int habs = (w * 2 + n) * 16;
      short8 w8;
      if (kk < 9) {
        const float* wrow = W + (size_t)(habs + t) * EE + kk * 32 + quad * 8;
        float4 f0 = *(const float4*)(wrow);
        float4 f1 = *(const float4*)(wrow + 4);
        w8[0] = f2bf(f0.x); w8[1] = f2bf(f0.y); w8[2] = f2bf(f0.z); w8[3] = f2bf(f0.w);
        w8[4] = f2bf(f1.x); w8[5] = f2bf(f1.y); w8[6] = f2bf(f1.z); w8[7] = f2bf(f1.w);
      } else {
#pragma unroll
        for (int jj = 0; jj < 8; ++jj) {
          int k = 288 + quad * 8 + jj;
          w8[jj] = (k < EE) ? f2bf(W[(size_t)(habs + t) * EE + k]) : (short)0;
        }
      }
      acc1[n] = MFMA16(a, w8, acc1[n]);   // q in quad-dim, h in t-dim  -> qlT
      acc2[n] = MFMA16(w8, a, acc2[n]);   // h in quad-dim, q in t-dim  -> ql
    }
  }
#pragma unroll
  for (int n = 0; n < 2; ++n) {
    const int habs = (w * 2 + n) * 16;
    const float bv1 = bias[habs + t];
    bhalf4 s1;
#pragma unroll
    for (int r = 0; r < 4; ++r) s1[r] = f2bf(fmaxf(acc1[n][r] + bv1, 0.0f));
    *(bhalf4*)&qlT[((size_t)b * HH + habs + t) * SQ + q0 + quad * 4] = s1;
    const float4 bv2 = *(const float4*)(bias + habs + quad * 4);
    bhalf4 s2;
    s2[0] = f2bf(fmaxf(acc2[n][0] + bv2.x, 0.0f));
    s2[1] = f2bf(fmaxf(acc2[n][1] + bv2.y, 0.0f));
    s2[2] = f2bf(fmaxf(acc2[n][2] + bv2.z, 0.0f));
    s2[3] = f2bf(fmaxf(acc2[n][3] + bv2.w, 0.0f));
    *(bhalf4*)&ql[((size_t)b * SQ + q0 + t) * HH + habs + quad * 4] = s2;
  }
}

// ---------------- kernel 2: fused ctx-logits + QK^T + softmax (no-max) + PV ------------
// UNCHANGED from R19 (clean attribution: this round touches only k_qlog/k_wpad).
// grid (SCTX/64, B) = 512 blocks; 4 waves; wave w owns ctx rows m0+w*16..+15, full q.
// LEDGER: R11 global-B = latency collapse. R14 tr_b16 = wrong elem order. R15 reg dbuf =
//   scratch spills. R12/R16/R17 staging variants + ILP batching ~40us. R18 occupancy 2x
//   REGRESSED (56us). R19 counted-vmcnt dbuf = no change (~40us). k_attn plateau ~40us.
__global__ __launch_bounds__(256, 2) void k_attn(const float* __restrict__ ctx,
                                                 const short* __restrict__ wsw,
                                                 const float* __restrict__ bias,
                                                 const int* __restrict__ mask,
                                                 const short* __restrict__ ql,
                                                 const short* __restrict__ qlT,
                                                 float* __restrict__ out) {
  const int b = blockIdx.y;
  const int m0 = blockIdx.x * 64;
  const int tid = threadIdx.x;
  const int w = tid >> 6, l = tid & 63, t = l & 15, quad = l >> 4;
  const int g = w >> 1, hf = w & 1;

  __shared__ __align__(16) short uq[16384];  // cst [32][328] | qbuf0,qbuf1 [64][128]
  __shared__ __align__(16) short uv[16384];  // clt [64][136] | vbuf0,vbuf1 [128][64]
  __shared__ __align__(16) short maskh[SQ];  // bf16 mask+exp-centering offsets
  short* cst = uq;
  short* clt = uv;
  short* qb0 = uq;          short* qb1 = uq + 8192;
  short* vb0 = uv;          short* vb1 = uv + 8192;

  for (int i = tid; i < SQ; i += 256)
    maskh[i] = f2bf(mask[b * SQ + i] ? -8.0f : -1e30f);  // -8 = exp-centering offset

  // ---- phase A: ctx_logits tile [64][128], two 32-row halves ----
  for (int i = 0; i < 2; ++i) {
    const float4* cbase = (const float4*)(ctx + ((size_t)b * SCTX + m0 + i * 32) * EE);
#pragma unroll
    for (int j = 0; j < 10; ++j) {
      int i4 = tid + j * 256;
      if (i4 < 2400) {
        float4 v = cbase[i4];
        int row = i4 / 75, c4 = i4 - row * 75;
        bhalf4 s4; s4[0] = f2bf(v.x); s4[1] = f2bf(v.y); s4[2] = f2bf(v.z); s4[3] = f2bf(v.w);
        *(bhalf4*)(cst + row * CST + c4 * 4) = s4;
      }
    }
    for (int k = tid; k < 320; k += 256) {
      int row = k / 10, c = (k - row * 10) * 2;
      *(int*)&cst[row * CST + 300 + c] = 0;
    }
    __syncthreads();
    const short* arow = cst + (g * 16 + t) * CST;
    f32x4 acc[4] = {};
#pragma unroll
    for (int kk = 0; kk < 10; ++kk) {
      const int k = kk * 32 + quad * 8;
      short8 a = *(const short8*)(arow + k);
      short8 w8[4];
#pragma unroll
      for (int n = 0; n < 4; ++n)
        w8[n] = *(const short8*)(wsw + ((kk * 8 + hf * 4 + n) * 64 + l) * 8);
#pragma unroll
      for (int n = 0; n < 4; ++n) acc[n] = MFMA16(a, w8[n], acc[n]);
    }
#pragma unroll
    for (int n = 0; n < 4; ++n) {
      const int h = (hf * 4 + n) * 16 + t;
      const float bv = bias[h];
#pragma unroll
      for (int r = 0; r < 4; ++r) {
        float v = fmaxf(acc[n][r] + bv, 0.0f);
        clt[(i * 32 + g * 16 + quad * 4 + r) * 136 + h] = f2bf(v);
      }
    }
    __syncthreads();  // clt written; cst free
  }

  // A-fragments for this wave's 16 ctx rows
  short8 af[4];
#pragma unroll
  for (int kk = 0; kk < 4; ++kk)
    af[kk] = *(const short8*)&clt[(w * 16 + t) * 136 + kk * 32 + quad * 8];
  __syncthreads();  // ALL waves' af (clt) reads drained before DMA overwrites uq/uv

  // ---- chunk machinery ----
  const int srcA = ((quad & 1) * 2) * 16 + t;  // shfl source lanes for P-assembly
  const int srcB = srcA + 16;
  const bool hiq = quad >= 2;
  const int sx  = (t & 7) << 3;   // read-side XOR (shorts)
  const int rl4 = l >> 4;         // DMA row-within-call (qbuf)
  const int cbq = (l & 15) * 16;  // DMA linear col-byte in 256-B q-row
  const int rl8 = l >> 3;         // DMA row-within-call (vbuf)
  const int cbv = (l & 7) * 16;   // DMA linear col-byte in 128-B h-row

  auto stageTo = [&](short* qb, short* vb, int c) {
#pragma unroll
    for (int s = 0; s < 4; ++s) {
      const int row = w * 16 + s * 4 + rl4;
      gload16((const char*)(ql + ((size_t)b * SQ + c * 64 + row) * HH) +
                  (cbq ^ ((row & 7) << 4)),
              qb + (w * 16 + s * 4) * 128);
    }
#pragma unroll
    for (int s = 0; s < 4; ++s) {
      const int row = w * 32 + s * 8 + rl8;
      gload16((const char*)(qlT + ((size_t)b * HH + row) * SQ + c * 64) +
                  (cbv ^ ((row & 7) << 4)),
              vb + (w * 32 + s * 8) * 64);
    }
  };

  stageTo(qb0, vb0, 0);
  stageTo(qb1, vb1, 1);

  f32x4 o[8] = {};
  float rtot = 0.0f;
  for (int c = 0; c < 8; ++c) {
    short* qch = (c & 1) ? qb1 : qb0;
    short* vch = (c & 1) ? vb1 : vb0;
    if (c < 7) { asm volatile("s_waitcnt vmcnt(8)" ::: "memory"); }
    else       { asm volatile("s_waitcnt vmcnt(0)" ::: "memory"); }
    SCHED0(); SBAR(); SCHED0();

    // ---- S: 16 MFMA (operand-swapped) ----
    f32x4 sv[4] = {};
#pragma unroll
    for (int n2 = 0; n2 < 4; ++n2) {
      const short* qr = qch + (n2 * 16 + t) * 128;
#pragma unroll
      for (int kx = 0; kx < 4; ++kx) {
        short8 b8 = *(const short8*)(qr + ((kx * 32 + quad * 8) ^ sx));
        sv[n2] = MFMA16(b8, af[kx], sv[n2]);
      }
    }
    // ---- E: mask + exp + pack ----
    unsigned pk[8];
#pragma unroll
    for (int n2 = 0; n2 < 4; ++n2) {
      bhalf4 mb = *(const bhalf4*)&maskh[c * 64 + n2 * 16 + quad * 4];
      float p0 = exp2f((sv[n2][0] + bf2f(mb[0])) * LOG2E);
      float p1 = exp2f((sv[n2][1] + bf2f(mb[1])) * LOG2E);
      float p2 = exp2f((sv[n2][2] + bf2f(mb[2])) * LOG2E);
      float p3 = exp2f((sv[n2][3] + bf2f(mb[3])) * LOG2E);
      rtot += (p0 + p1) + (p2 + p3);
      pk[n2 * 2 + 0] = pack2(p0, p1);
      pk[n2 * 2 + 1] = pack2(p2, p3);
    }
    // ---- X: 16 shuffles ----
    unsigned sA[8], sB[8];
#pragma unroll
    for (int i = 0; i < 8; ++i) {
      sA[i] = (unsigned)__shfl((int)pk[i], srcA);
      sB[i] = (unsigned)__shfl((int)pk[i], srcB);
    }
    // ---- PV: 16 MFMA ----
#pragma unroll
    for (int kk2 = 0; kk2 < 2; ++kk2) {
      u32x4 av;
      av[0] = hiq ? sA[kk2 * 4 + 2] : sA[kk2 * 4 + 0];
      av[1] = hiq ? sA[kk2 * 4 + 3] : sA[kk2 * 4 + 1];
      av[2] = hiq ? sB[kk2 * 4 + 2] : sB[kk2 * 4 + 0];
      av[3] = hiq ? sB[kk2 * 4 + 3] : sB[kk2 * 4 + 1];
      short8 pa = __builtin_bit_cast(short8, av);
      const int co = (kk2 * 32 + quad * 8) ^ sx;
#pragma unroll
      for (int n = 0; n < 8; ++n) {
        short8 v8 = *(const short8*)&vch[(n * 16 + t) * 64 + co];
        o[n] = MFMA16(pa, v8, o[n]);
      }
    }
    if (c < 7) {
      asm volatile("s_waitcnt lgkmcnt(0)" ::: "memory");
      SCHED0(); SBAR(); SCHED0();
      if (c < 6) stageTo(qch, vch, c + 2);
    }
  }

  // ---- epilogue ----
  rtot += __shfl_xor(rtot, 16);
  rtot += __shfl_xor(rtot, 32);
  f32x4 rinv;
#pragma unroll
  for (int r = 0; r < 4; ++r) rinv[r] = 1.0f / __shfl(rtot, quad * 4 + r);
  float* obase = out + ((size_t)b * SCTX + m0 + w * 16) * HH;
#pragma unroll
  for (int n = 0; n < 8; ++n)
#pragma unroll
    for (int r = 0; r < 4; ++r)
      obase[(quad * 4 + r) * HH + n * 16 + t] = o[n][r] * rinv[r];
}

extern "C" void kernel_launch(void* const* d_in, const int* in_sizes, int n_in,
                              void* d_out, int out_size, void* d_ws, size_t ws_size,
                              hipStream_t stream) {
  const float* ctx  = (const float*)d_in[0];
  const float* qst  = (const float*)d_in[1];
  const int*   mask = (const int*)d_in[2];
  const float* W    = (const float*)d_in[3];
  const float* bias = (const float*)d_in[4];
  float* out = (float*)d_out;

  // ws: wsw 80 KiB | ql 1 MiB | qlT 1 MiB
  short* wsw  = (short*)d_ws;
  short* ql   = (short*)((char*)d_ws + 81920);
  short* qlT  = ql + (size_t)BB * SQ * HH;

  k_qlog<<<dim3(SQ / 16, BB), dim3(256), 0, stream>>>(qst, W, bias, ql, qlT, wsw);
  k_attn<<<dim3(SCTX / 64, BB), dim3(256), 0, stream>>>(ctx, wsw, bias, mask, ql, qlT, out);
}

// Round 11
// 117.562 us; speedup vs baseline: 1.0591x; 1.0591x over previous
//
#include <hip/hip_runtime.h>
#include <hip/hip_bf16.h>

#define BB   8
#define SCTX 4096
#define SQ   512
#define EE   300
#define HH   128
#define EP   320    // E padded to multiple of 32
#define CST  328    // staged fp32->bf16 E-row stride (shorts)
#define LOG2E 1.4426950408889634f

// HIP predefines short4/float4/uint4 (hip_vector_types.h) — never shadow them.
typedef short bhalf4 __attribute__((ext_vector_type(4)));
typedef short short8 __attribute__((ext_vector_type(8)));
typedef float f32x4  __attribute__((ext_vector_type(4)));
typedef unsigned u32x4 __attribute__((ext_vector_type(4)));

#define MFMA16(a, b, c) __builtin_amdgcn_mfma_f32_16x16x32_bf16((a), (b), (c), 0, 0, 0)

__device__ __forceinline__ short f2bf(float f) {
  unsigned u = __builtin_bit_cast(unsigned, f);
  u += 0x7fffu + ((u >> 16) & 1u);
  return (short)(u >> 16);
}
__device__ __forceinline__ float bf2f(short s) {
  return __builtin_bit_cast(float, ((unsigned)(unsigned short)s) << 16);
}
__device__ __forceinline__ unsigned pack2(float a, float b) {
  return (unsigned)(unsigned short)f2bf(a) | ((unsigned)(unsigned short)f2bf(b) << 16);
}
// global -> LDS direct DMA, 16 B/lane. LDS dest = wave-uniform base + lane*16 (m104);
// global source is per-lane (swizzle goes on the SOURCE, rule #21).
__device__ __forceinline__ void gload16(const void* g, void* lds) {
  __builtin_amdgcn_global_load_lds(
      (const __attribute__((address_space(1))) void*)g,
      (__attribute__((address_space(3))) void*)lds, 16, 0, 0);
}

// ---------------- kernel 0: W (fp32 [128][300]) -> bf16 fragment-swizzled wsw ---------
// wsw element for W[h][k]: m=h>>4, t=h&15, kk=k>>5, quad=(k>>3)&3, j=k&7
//   wsw[((kk*8 + m)*64 + quad*16 + t)*8 + j]
// -> a wave reading frag (kk, m) issues one fully-coalesced 64-lane x 16 B load.
// (A- and B-operand fragment layouts of mfma_16x16x32 are IDENTICAL — lane: row l&15,
//  k (l>>4)*8 — so the same wsw fragment serves both operand positions.)
__global__ void k_wpad(const float* __restrict__ W, short* __restrict__ wsw) {
  const int h = blockIdx.x, k = threadIdx.x;
  float v = (k < EE) ? W[h * EE + k] : 0.0f;
  const int m = h >> 4, t = h & 15, kk = k >> 5, quad = (k >> 3) & 3, j = k & 7;
  wsw[((kk * 8 + m) * 64 + quad * 16 + t) * 8 + j] = f2bf(v);
}

// ---------------- kernel 1: qst logits -> ql [b][q][h] + qlT [b][h][q] ---------------
// R21 = R20's structure (256 blocks, dual-layout MFMA, all-b64 stores — verified
// bit-identical) with R20's one regression fixed: W fragments come from wsw again
// (one coalesced 64-lane x 16-B load each), NOT per-lane strided global W reads
// (R20: 20 uncoalesced 32-B/lane loads/thread = the +3us). k_wpad restored.
//   acc1 = MFMA16(a, w8): lane(t,quad) r = QL[q=q0+quad*4+r][h=habs+t] -> qlT b64
//   acc2 = MFMA16(w8, a): lane(t,quad) r = QL[q=q0+t][h=habs+quad*4+r] -> ql  b64
// (D-layout rule verified R15/R18/R20: D[lane(t,quad),r] = Arow(quad*4+r) . Brow(t).)
__global__ __launch_bounds__(256) void k_qlog(const float* __restrict__ qst,
                                              const short* __restrict__ wsw,
                                              const float* __restrict__ bias,
                                              short* __restrict__ ql,
                                              short* __restrict__ qlT) {
  const int b = blockIdx.y;
  const int q0 = blockIdx.x * 16;
  const int tid = threadIdx.x;
  const int w = tid >> 6, l = tid & 63, t = l & 15, quad = l >> 4;

  __shared__ __align__(16) short cst[16 * CST];

  // stage 16 q-rows fp32 -> bf16 (1200 float4)
  const float4* cbase = (const float4*)(qst + (size_t)(b * SQ + q0) * EE);
#pragma unroll
  for (int j = 0; j < 5; ++j) {
    int i4 = tid + j * 256;
    if (i4 < 1200) {
      float4 v = cbase[i4];
      int row = i4 / 75, c4 = i4 - row * 75;
      bhalf4 s4; s4[0] = f2bf(v.x); s4[1] = f2bf(v.y); s4[2] = f2bf(v.z); s4[3] = f2bf(v.w);
      *(bhalf4*)(cst + row * CST + c4 * 4) = s4;
    }
  }
  for (int i = tid; i < 160; i += 256) {        // zero k=300..319 for all 16 rows
    int row = i / 10, c = (i - row * 10) * 2;
    *(int*)&cst[row * CST + 300 + c] = 0;
  }
  __syncthreads();

  // per-wave: h-blocks m ∈ {2w, 2w+1}; dual-layout accumulate (40 MFMA/wave)
  f32x4 acc1[2] = {}, acc2[2] = {};
  const short* arow = cst + t * CST;
#pragma unroll
  for (int kk = 0; kk < 10; ++kk) {
    short8 a = *(const short8*)(arow + kk * 32 + quad * 8);
#pragma unroll
    for (int n = 0; n < 2; ++n) {
      const int m = w * 2 + n;
      short8 w8 = *(const short8*)(wsw + ((kk * 8 + m) * 64 + l) * 8);  // coalesced
      acc1[n] = MFMA16(a, w8, acc1[n]);   // q in quad-dim, h in t-dim  -> qlT
      acc2[n] = MFMA16(w8, a, acc2[n]);   // h in quad-dim, q in t-dim  -> ql
    }
  }
#pragma unroll
  for (int n = 0; n < 2; ++n) {
    const int habs = (w * 2 + n) * 16;
    const float bv1 = bias[habs + t];
    bhalf4 s1;
#pragma unroll
    for (int r = 0; r < 4; ++r) s1[r] = f2bf(fmaxf(acc1[n][r] + bv1, 0.0f));
    *(bhalf4*)&qlT[((size_t)b * HH + habs + t) * SQ + q0 + quad * 4] = s1;
    const float4 bv2 = *(const float4*)(bias + habs + quad * 4);
    bhalf4 s2;
    s2[0] = f2bf(fmaxf(acc2[n][0] + bv2.x, 0.0f));
    s2[1] = f2bf(fmaxf(acc2[n][1] + bv2.y, 0.0f));
    s2[2] = f2bf(fmaxf(acc2[n][2] + bv2.z, 0.0f));
    s2[3] = f2bf(fmaxf(acc2[n][3] + bv2.w, 0.0f));
    *(bhalf4*)&ql[((size_t)b * SQ + q0 + t) * HH + habs + quad * 4] = s2;
  }
}

// ---------------- kernel 2: fused ctx-logits + QK^T + softmax (no-max) + PV ------------
// grid (SCTX/64, B) = 512 blocks; 4 waves; wave w owns ctx rows m0+w*16..+15, full q.
//
// LEDGER: R11 global-B = latency collapse. R14 tr_b16 = wrong elem order. R15 reg dbuf =
//   scratch spills. R12/R16/R17 staging variants + ILP batching ~40us. R18 occupancy 2x
//   REGRESSED (56us; confounded with 2x phase-A work). R19 counted-vmcnt dbuf = no
//   change. k_attn plateau ~40us across 5 structural attacks.
// R21: guide-T3 minimum-2-phase loop — ONE __syncthreads per chunk (8 vs R19's 14
//   chunk-barriers + asm waits). At the barrier the only outstanding vmem is chunk c's
//   DMA issued a FULL chunk earlier (drain free); stage(c+1) right after the barrier
//   into the other buffer (its readers = chunk c-1, drained at this barrier: each
//   wave's c-1 ds_reads were consumed by MFMAs before it arrived). No inline asm.
// Max-subtraction dropped (S_max ~16 << 88; -8 centering in maskh; R10-verified).
// __launch_bounds__ min-waves MUST stay 2 (3 => spill binary, R6/R8).
__global__ __launch_bounds__(256, 2) void k_attn(const float* __restrict__ ctx,
                                                 const short* __restrict__ wsw,
                                                 const float* __restrict__ bias,
                                                 const int* __restrict__ mask,
                                                 const short* __restrict__ ql,
                                                 const short* __restrict__ qlT,
                                                 float* __restrict__ out) {
  const int b = blockIdx.y;
  const int m0 = blockIdx.x * 64;
  const int tid = threadIdx.x;
  const int w = tid >> 6, l = tid & 63, t = l & 15, quad = l >> 4;
  const int g = w >> 1, hf = w & 1;

  __shared__ __align__(16) short uq[16384];  // cst [32][328] | qbuf0,qbuf1 [64][128]
  __shared__ __align__(16) short uv[16384];  // clt [64][136] | vbuf0,vbuf1 [128][64]
  __shared__ __align__(16) short maskh[SQ];  // bf16 mask+exp-centering offsets
  short* cst = uq;
  short* clt = uv;
  short* qb0 = uq;          short* qb1 = uq + 8192;
  short* vb0 = uv;          short* vb1 = uv + 8192;

  for (int i = tid; i < SQ; i += 256)
    maskh[i] = f2bf(mask[b * SQ + i] ? -8.0f : -1e30f);  // -8 = exp-centering offset

  // ---- phase A: ctx_logits tile [64][128], two 32-row halves ----
  for (int i = 0; i < 2; ++i) {
    const float4* cbase = (const float4*)(ctx + ((size_t)b * SCTX + m0 + i * 32) * EE);
#pragma unroll
    for (int j = 0; j < 10; ++j) {
      int i4 = tid + j * 256;
      if (i4 < 2400) {
        float4 v = cbase[i4];
        int row = i4 / 75, c4 = i4 - row * 75;
        bhalf4 s4; s4[0] = f2bf(v.x); s4[1] = f2bf(v.y); s4[2] = f2bf(v.z); s4[3] = f2bf(v.w);
        *(bhalf4*)(cst + row * CST + c4 * 4) = s4;
      }
    }
    for (int k = tid; k < 320; k += 256) {
      int row = k / 10, c = (k - row * 10) * 2;
      *(int*)&cst[row * CST + 300 + c] = 0;
    }
    __syncthreads();
    const short* arow = cst + (g * 16 + t) * CST;
    f32x4 acc[4] = {};
#pragma unroll
    for (int kk = 0; kk < 10; ++kk) {
      const int k = kk * 32 + quad * 8;
      short8 a = *(const short8*)(arow + k);
      short8 w8[4];
#pragma unroll
      for (int n = 0; n < 4; ++n)
        w8[n] = *(const short8*)(wsw + ((kk * 8 + hf * 4 + n) * 64 + l) * 8);
#pragma unroll
      for (int n = 0; n < 4; ++n) acc[n] = MFMA16(a, w8[n], acc[n]);
    }
#pragma unroll
    for (int n = 0; n < 4; ++n) {
      const int h = (hf * 4 + n) * 16 + t;
      const float bv = bias[h];
#pragma unroll
      for (int r = 0; r < 4; ++r) {
        float v = fmaxf(acc[n][r] + bv, 0.0f);
        clt[(i * 32 + g * 16 + quad * 4 + r) * 136 + h] = f2bf(v);
      }
    }
    __syncthreads();  // clt written; cst free
  }

  // A-fragments for this wave's 16 ctx rows
  short8 af[4];
#pragma unroll
  for (int kk = 0; kk < 4; ++kk)
    af[kk] = *(const short8*)&clt[(w * 16 + t) * 136 + kk * 32 + quad * 8];
  __syncthreads();  // ALL waves' af (clt) reads drained before DMA overwrites uq/uv

  // ---- chunk machinery ----
  const int srcA = ((quad & 1) * 2) * 16 + t;  // shfl source lanes for P-assembly
  const int srcB = srcA + 16;
  const bool hiq = quad >= 2;
  const int sx  = (t & 7) << 3;   // read-side XOR (shorts)
  const int rl4 = l >> 4;         // DMA row-within-call (qbuf)
  const int cbq = (l & 15) * 16;  // DMA linear col-byte in 256-B q-row
  const int rl8 = l >> 3;         // DMA row-within-call (vbuf)
  const int cbv = (l & 7) * 16;   // DMA linear col-byte in 128-B h-row

  auto stageTo = [&](short* qb, short* vb, int c) {
#pragma unroll
    for (int s = 0; s < 4; ++s) {
      const int row = w * 16 + s * 4 + rl4;
      gload16((const char*)(ql + ((size_t)b * SQ + c * 64 + row) * HH) +
                  (cbq ^ ((row & 7) << 4)),
              qb + (w * 16 + s * 4) * 128);
    }
#pragma unroll
    for (int s = 0; s < 4; ++s) {
      const int row = w * 32 + s * 8 + rl8;
      gload16((const char*)(qlT + ((size_t)b * HH + row) * SQ + c * 64) +
                  (cbv ^ ((row & 7) << 4)),
              vb + (w * 32 + s * 8) * 64);
    }
  };

  stageTo(qb0, vb0, 0);  // only exposed DMA wait: drained at the first chunk barrier

  f32x4 o[8] = {};
  float rtot = 0.0f;
  for (int c = 0; c < 8; ++c) {
    short* qch = (c & 1) ? qb1 : qb0;
    short* vch = (c & 1) ? vb1 : vb0;
    // ONE barrier/chunk: drains chunk c's DMA (the only outstanding vmem; issued a
    // full chunk ago) and orders all waves past chunk c-1's reads.
    __syncthreads();
    if (c < 7) stageTo((c & 1) ? qb0 : qb1, (c & 1) ? vb0 : vb1, c + 1);

    // ---- S: 16 MFMA (operand-swapped) ----
    f32x4 sv[4] = {};
#pragma unroll
    for (int n2 = 0; n2 < 4; ++n2) {
      const short* qr = qch + (n2 * 16 + t) * 128;
#pragma unroll
      for (int kx = 0; kx < 4; ++kx) {
        short8 b8 = *(const short8*)(qr + ((kx * 32 + quad * 8) ^ sx));
        sv[n2] = MFMA16(b8, af[kx], sv[n2]);
      }
    }
    // ---- E: mask + exp + pack; lane(t,quad) r = P[q=c*64+n2*16+quad*4+r][ctx=t] ----
    unsigned pk[8];
#pragma unroll
    for (int n2 = 0; n2 < 4; ++n2) {
      bhalf4 mb = *(const bhalf4*)&maskh[c * 64 + n2 * 16 + quad * 4];
      float p0 = exp2f((sv[n2][0] + bf2f(mb[0])) * LOG2E);
      float p1 = exp2f((sv[n2][1] + bf2f(mb[1])) * LOG2E);
      float p2 = exp2f((sv[n2][2] + bf2f(mb[2])) * LOG2E);
      float p3 = exp2f((sv[n2][3] + bf2f(mb[3])) * LOG2E);
      rtot += (p0 + p1) + (p2 + p3);
      pk[n2 * 2 + 0] = pack2(p0, p1);
      pk[n2 * 2 + 1] = pack2(p2, p3);
    }
    // ---- X: 16 shuffles ----
    unsigned sA[8], sB[8];
#pragma unroll
    for (int i = 0; i < 8; ++i) {
      sA[i] = (unsigned)__shfl((int)pk[i], srcA);
      sB[i] = (unsigned)__shfl((int)pk[i], srcB);
    }
    // ---- PV: 16 MFMA ----
#pragma unroll
    for (int kk2 = 0; kk2 < 2; ++kk2) {
      u32x4 av;
      av[0] = hiq ? sA[kk2 * 4 + 2] : sA[kk2 * 4 + 0];
      av[1] = hiq ? sA[kk2 * 4 + 3] : sA[kk2 * 4 + 1];
      av[2] = hiq ? sB[kk2 * 4 + 2] : sB[kk2 * 4 + 0];
      av[3] = hiq ? sB[kk2 * 4 + 3] : sB[kk2 * 4 + 1];
      short8 pa = __builtin_bit_cast(short8, av);
      const int co = (kk2 * 32 + quad * 8) ^ sx;
#pragma unroll
      for (int n = 0; n < 8; ++n) {
        short8 v8 = *(const short8*)&vch[(n * 16 + t) * 64 + co];
        o[n] = MFMA16(pa, v8, o[n]);
      }
    }
  }

  // ---- epilogue (register/shuffle only) ----
  rtot += __shfl_xor(rtot, 16);
  rtot += __shfl_xor(rtot, 32);  // lane x holds full denom for ctx row (x&15)
  f32x4 rinv;
#pragma unroll
  for (int r = 0; r < 4; ++r) rinv[r] = 1.0f / __shfl(rtot, quad * 4 + r);
  float* obase = out + ((size_t)b * SCTX + m0 + w * 16) * HH;
#pragma unroll
  for (int n = 0; n < 8; ++n)
#pragma unroll
    for (int r = 0; r < 4; ++r)
      obase[(quad * 4 + r) * HH + n * 16 + t] = o[n][r] * rinv[r];
}

extern "C" void kernel_launch(void* const* d_in, const int* in_sizes, int n_in,
                              void* d_out, int out_size, void* d_ws, size_t ws_size,
                              hipStream_t stream) {
  const float* ctx  = (const float*)d_in[0];
  const float* qst  = (const float*)d_in[1];
  const int*   mask = (const int*)d_in[2];
  const float* W    = (const float*)d_in[3];
  const float* bias = (const float*)d_in[4];
  float* out = (float*)d_out;

  // ws: wsw 80 KiB | ql 1 MiB | qlT 1 MiB
  short* wsw  = (short*)d_ws;
  short* ql   = (short*)((char*)d_ws + 81920);
  short* qlT  = ql + (size_t)BB * SQ * HH;

  k_wpad<<<dim3(HH), dim3(EP), 0, stream>>>(W, wsw);
  k_qlog<<<dim3(SQ / 16, BB), dim3(256), 0, stream>>>(qst, wsw, bias, ql, qlT);
  k_attn<<<dim3(SCTX / 64, BB), dim3(256), 0, stream>>>(ctx, wsw, bias, mask, ql, qlT, out);
}